// Round 3
// baseline (420.223 us; speedup 1.0000x reference)
//
#include <hip/hip_runtime.h>
#include <hip/hip_bf16.h>
#include <stdint.h>

#define NN 8192
#define FIN 512
#define HID 256

typedef short bf16x8 __attribute__((ext_vector_type(8)));
typedef float f32x4 __attribute__((ext_vector_type(4)));

__device__ __forceinline__ uint32_t pk2(float lo, float hi) {
  uint32_t a = __float_as_uint(lo), b = __float_as_uint(hi);
  a = (a + 0x7FFFu + ((a >> 16) & 1u)) >> 16;
  b = (b + 0x7FFFu + ((b >> 16) & 1u)) >> 16;
  return a | (b << 16);
}

// workspace byte offsets
#define OFF_SEQB   0u         // 8192*512*2  = 8388608
#define OFF_WTB    8388608u   // 256*512*2   = 262144
#define OFF_FTST   8650752u   // 256*8192*2  = 4194304
#define OFF_F1     12845056u  // 8192*4
#define OFF_F2     12877824u  // 8192*4
#define OFF_Z      12910592u  // 8192*4
#define OFF_F2MAX  12943360u  // 4

// ---- seq f32 -> bf16 ----
__global__ void k_cvt_seq(const float* __restrict__ seq, short* __restrict__ seqb) {
  int i = (blockIdx.x * 256 + threadIdx.x) * 4;
  float4 v = *(const float4*)(seq + i);
  uint2 o; o.x = pk2(v.x, v.y); o.y = pk2(v.z, v.w);
  *(uint2*)(seqb + i) = o;
}

// ---- W[512,256] -> WT bf16 [256,512] ----
__global__ void k_wt(const float* __restrict__ W, short* __restrict__ WTb) {
  int h = blockIdx.x;   // 0..255
  int t = threadIdx.x;  // 0..255
  int k = t * 2;
  float w0 = W[k * 256 + h], w1 = W[(k + 1) * 256 + h];
  ((uint32_t*)(WTb + h * 512))[t] = pk2(w0, w1);
}

// ---- projection GEMM: fts = seq@W (bf16 MFMA); epilogue: ftsT, f1, f2, f2max ----
__global__ __launch_bounds__(256) void k_proj(
    const short* __restrict__ seqb, const short* __restrict__ WTb,
    const float* __restrict__ a1, const float* __restrict__ b1,
    const float* __restrict__ a2, const float* __restrict__ b2,
    short* __restrict__ ftsT, float* __restrict__ f1g, float* __restrict__ f2g,
    uint32_t* __restrict__ f2maxenc) {
  __shared__ short At[64][72];
  __shared__ float f1a[64], f2a[64];
  const int t = threadIdx.x;
  const int l = t & 63, w = t >> 6;
  const int lr = l & 15, lg = l >> 4;
  const int R0 = blockIdx.x * 64;
  const int srow = t >> 2, scol = (t & 3) * 16;
  f32x4 acc[4][4] = {};
  if (t < 64) { f1a[t] = 0.f; f2a[t] = 0.f; }
  for (int kt = 0; kt < FIN; kt += 64) {
    uint4 s0 = *(const uint4*)(seqb + (size_t)(R0 + srow) * FIN + kt + scol);
    uint4 s1 = *(const uint4*)(seqb + (size_t)(R0 + srow) * FIN + kt + scol + 8);
    __syncthreads();
    *(uint4*)&At[srow][scol] = s0;
    *(uint4*)&At[srow][scol + 8] = s1;
    __syncthreads();
#pragma unroll
    for (int kk = 0; kk < 2; ++kk) {
      bf16x8 af[4];
#pragma unroll
      for (int mf = 0; mf < 4; ++mf)
        af[mf] = *(const bf16x8*)&At[mf * 16 + lr][kk * 32 + lg * 8];
#pragma unroll
      for (int nf = 0; nf < 4; ++nf) {
        int h = w * 64 + nf * 16 + lr;
        bf16x8 bfr = *(const bf16x8*)(WTb + h * FIN + kt + kk * 32 + lg * 8);
#pragma unroll
        for (int mf = 0; mf < 4; ++mf)
          acc[mf][nf] = __builtin_amdgcn_mfma_f32_16x16x32_bf16(af[mf], bfr, acc[mf][nf], 0, 0, 0);
      }
    }
  }
  __syncthreads();
  float a1v[4], a2v[4];
#pragma unroll
  for (int nf = 0; nf < 4; ++nf) {
    int h = w * 64 + nf * 16 + lr;
    a1v[nf] = a1[h]; a2v[nf] = a2[h];
  }
#pragma unroll
  for (int mf = 0; mf < 4; ++mf) {
#pragma unroll
    for (int nf = 0; nf < 4; ++nf) {  // ftsT[h][i] bf16 store
      int h = w * 64 + nf * 16 + lr;
      int r0 = R0 + mf * 16 + lg * 4;
      uint2 o; o.x = pk2(acc[mf][nf][0], acc[mf][nf][1]);
      o.y = pk2(acc[mf][nf][2], acc[mf][nf][3]);
      *(uint2*)(ftsT + (size_t)h * NN + r0) = o;
    }
#pragma unroll
    for (int e = 0; e < 4; ++e) {
      float p1 = 0.f, p2 = 0.f;
#pragma unroll
      for (int nf = 0; nf < 4; ++nf) { p1 += acc[mf][nf][e] * a1v[nf]; p2 += acc[mf][nf][e] * a2v[nf]; }
#pragma unroll
      for (int m = 8; m >= 1; m >>= 1) { p1 += __shfl_xor(p1, m, 16); p2 += __shfl_xor(p2, m, 16); }
      if (lr == 0) {
        atomicAdd(&f1a[mf * 16 + lg * 4 + e], p1);
        atomicAdd(&f2a[mf * 16 + lg * 4 + e], p2);
      }
    }
  }
  __syncthreads();
  if (t < 64) {
    float v1 = f1a[t] + b1[0];
    float v2 = f2a[t] + b2[0];
    f1g[R0 + t] = v1; f2g[R0 + t] = v2;
    uint32_t u = __float_as_uint(v2);
    u = (u & 0x80000000u) ? ~u : (u | 0x80000000u);  // order-preserving encode
    atomicMax(f2maxenc, u);
  }
}

// ---- fused flash: E computed directly in MFMA A-frag layout; no LDS, no barriers ----
// Block: 256 thr = 4 waves, each wave owns 16 rows x all 256 h. Grid: (128 i-blocks, 8 j-chunks).
// Per 32-j step: lane computes its 8 probabilities (A row = lane&15, k = (lane>>4)*8+e),
// B-frags read from L1/L2-resident ftsT. Bias/f2 prefetched 2 steps ahead (static 2-stage regs).
__global__ __launch_bounds__(256, 3) void k_flash(
    const float* __restrict__ bias, const short* __restrict__ ftsT,
    const float* __restrict__ f1g, const float* __restrict__ f2g,
    const uint32_t* __restrict__ f2maxenc,
    float* __restrict__ outacc, float* __restrict__ Zg) {
  const int t = threadIdx.x;
  const int l = t & 63, wid = t >> 6;
  const int lr = l & 15, lg = l >> 4;
  const int rbase = blockIdx.x * 64 + wid * 16;
  const int rowA = rbase + lr;                 // this lane's A/E row
  const int jbase = blockIdx.y * 1024;
  uint32_t ue = *f2maxenc;
  float f2mx = __uint_as_float((ue & 0x80000000u) ? (ue ^ 0x80000000u) : ~ue);
  float f1v = f1g[rowA];
  float xm = f1v + f2mx;
  float mr = fmaxf(xm, 0.2f * xm);             // exact row max (bias<=0, lrelu monotone)

  const float* bp = bias + (size_t)rowA * NN + jbase + lg * 8;
  const float* qp = f2g + jbase + lg * 8;
  const short* fp = ftsT + (size_t)lr * NN + jbase + lg * 8;

  f32x4 acc[16] = {};
  float z = 0.f;

#define LD4(P, O) (*(const float4*)((P) + (O)))
  // two named prefetch stages (static indexing; rule: no runtime-indexed reg arrays)
  float4 b0a = LD4(bp, 0),  b1a = LD4(bp, 4),  q0a = LD4(qp, 0),  q1a = LD4(qp, 4);
  float4 b0b = LD4(bp, 32), b1b = LD4(bp, 36), q0b = LD4(qp, 32), q1b = LD4(qp, 36);

#define BODY(HK, B0, B1, Q0, Q1)                                              \
  {                                                                           \
    float p[8];                                                               \
    const float* bq0 = (const float*)&(B0); const float* fq0 = (const float*)&(Q0); \
    const float* bq1 = (const float*)&(B1); const float* fq1 = (const float*)&(Q1); \
    _Pragma("unroll")                                                         \
    for (int e = 0; e < 4; ++e) {                                             \
      float s = f1v + fq0[e]; float ls = fmaxf(s, 0.2f * s);                  \
      p[e] = __expf(ls + bq0[e] - mr);                                        \
    }                                                                         \
    _Pragma("unroll")                                                         \
    for (int e = 0; e < 4; ++e) {                                             \
      float s = f1v + fq1[e]; float ls = fmaxf(s, 0.2f * s);                  \
      p[4 + e] = __expf(ls + bq1[e] - mr);                                    \
    }                                                                         \
    z += ((p[0] + p[1]) + (p[2] + p[3])) + ((p[4] + p[5]) + (p[6] + p[7]));   \
    union { bf16x8 v; uint32_t u[4]; } A;                                     \
    A.u[0] = pk2(p[0], p[1]); A.u[1] = pk2(p[2], p[3]);                       \
    A.u[2] = pk2(p[4], p[5]); A.u[3] = pk2(p[6], p[7]);                       \
    const short* fpp = fp + (HK) * 32;                                        \
    _Pragma("unroll")                                                         \
    for (int nf = 0; nf < 16; ++nf) {                                         \
      bf16x8 B = *(const bf16x8*)(fpp + nf * 16 * NN);                        \
      acc[nf] = __builtin_amdgcn_mfma_f32_16x16x32_bf16(A.v, B, acc[nf], 0, 0, 0); \
    }                                                                         \
  }

  for (int hk = 0; hk < 32; hk += 2) {
    {  // even step: consume stage A, prefetch hk+2 into stage A
      float4 cb0 = b0a, cb1 = b1a, cq0 = q0a, cq1 = q1a;
      if (hk + 2 < 32) {
        b0a = LD4(bp, (hk + 2) * 32); b1a = LD4(bp, (hk + 2) * 32 + 4);
        q0a = LD4(qp, (hk + 2) * 32); q1a = LD4(qp, (hk + 2) * 32 + 4);
      }
      BODY(hk, cb0, cb1, cq0, cq1)
    }
    {  // odd step: consume stage B, prefetch hk+3 into stage B
      float4 cb0 = b0b, cb1 = b1b, cq0 = q0b, cq1 = q1b;
      if (hk + 3 < 32) {
        b0b = LD4(bp, (hk + 3) * 32); b1b = LD4(bp, (hk + 3) * 32 + 4);
        q0b = LD4(qp, (hk + 3) * 32); q1b = LD4(qp, (hk + 3) * 32 + 4);
      }
      BODY(hk + 1, cb0, cb1, cq0, cq1)
    }
  }
#undef BODY
#undef LD4

  // Z: reduce over lg groups (lanes differing in bits 4..5 share row lr)
  z += __shfl_xor(z, 16);
  z += __shfl_xor(z, 32);
  if (lg == 0) atomicAdd(&Zg[rowA], z);

  // numerator partials into d_out (C layout: row = lg*4+e, col = nf*16+lr)
#pragma unroll
  for (int nf = 0; nf < 16; ++nf) {
    int col = nf * 16 + lr;
#pragma unroll
    for (int e = 0; e < 4; ++e)
      atomicAdd(&outacc[(size_t)(rbase + lg * 4 + e) * HID + col], acc[nf][e]);
  }
}

// ---- finalize: out = elu(num/Z + bias_zero) ----
__global__ void k_final(float* __restrict__ outp, const float* __restrict__ Zg,
                        const float* __restrict__ bz) {
  int i4 = (blockIdx.x * 256 + threadIdx.x) * 4;
  int row = i4 >> 8;
  int col = i4 & 255;
  float4 v = *(float4*)(outp + i4);
  float zr = 1.0f / Zg[row];
  float4 b = *(const float4*)(bz + col);
  float r[4] = {v.x * zr + b.x, v.y * zr + b.y, v.z * zr + b.z, v.w * zr + b.w};
#pragma unroll
  for (int e = 0; e < 4; ++e) r[e] = r[e] > 0.f ? r[e] : (__expf(r[e]) - 1.f);
  *(float4*)(outp + i4) = make_float4(r[0], r[1], r[2], r[3]);
}

extern "C" void kernel_launch(void* const* d_in, const int* in_sizes, int n_in,
                              void* d_out, int out_size, void* d_ws, size_t ws_size,
                              hipStream_t stream) {
  const float* seq  = (const float*)d_in[0];
  const float* bias = (const float*)d_in[1];
  const float* W    = (const float*)d_in[2];
  const float* a1   = (const float*)d_in[3];
  const float* b1   = (const float*)d_in[4];
  const float* a2   = (const float*)d_in[5];
  const float* b2   = (const float*)d_in[6];
  const float* bz   = (const float*)d_in[7];
  float* out = (float*)d_out;
  char* ws = (char*)d_ws;
  short* seqb = (short*)(ws + OFF_SEQB);
  short* WTb  = (short*)(ws + OFF_WTB);
  short* ftsT = (short*)(ws + OFF_FTST);
  float* f1g  = (float*)(ws + OFF_F1);
  float* f2g  = (float*)(ws + OFF_F2);
  float* Zg   = (float*)(ws + OFF_Z);
  uint32_t* f2m = (uint32_t*)(ws + OFF_F2MAX);

  hipMemsetAsync(d_out, 0, (size_t)NN * HID * 4, stream);
  hipMemsetAsync(Zg, 0, NN * 4, stream);
  hipMemsetAsync(f2m, 0, 4, stream);

  k_cvt_seq<<<4096, 256, 0, stream>>>(seq, seqb);
  k_wt<<<256, 256, 0, stream>>>(W, WTb);
  k_proj<<<128, 256, 0, stream>>>(seqb, WTb, a1, b1, a2, b2, ftsT, f1g, f2g, f2m);
  k_flash<<<dim3(128, 8), 256, 0, stream>>>(bias, ftsT, f1g, f2g, f2m, out, Zg);
  k_final<<<2048, 256, 0, stream>>>(out, Zg, bz);
}

// Round 4
// 262.607 us; speedup vs baseline: 1.6002x; 1.6002x over previous
//
#include <hip/hip_runtime.h>
#include <hip/hip_bf16.h>
#include <stdint.h>

#define NN 8192
#define FIN 512
#define HID 256

typedef short bf16x8 __attribute__((ext_vector_type(8)));
typedef float f32x4 __attribute__((ext_vector_type(4)));

__device__ __forceinline__ uint32_t pk2(float lo, float hi) {
  uint32_t a = __float_as_uint(lo), b = __float_as_uint(hi);
  a = (a + 0x7FFFu + ((a >> 16) & 1u)) >> 16;
  b = (b + 0x7FFFu + ((b >> 16) & 1u)) >> 16;
  return a | (b << 16);
}

// workspace byte offsets
#define OFF_SEQB   0u         // 8192*512*2  = 8388608
#define OFF_WTB    8388608u   // 256*512*2   = 262144
#define OFF_FTST   8650752u   // 256*8192*2  = 4194304 (packed swizzled tiles)
#define OFF_F1     12845056u  // 8192*4
#define OFF_F2     12877824u  // 8192*4
#define OFF_Z      12910592u  // 8192*4
#define OFF_F2MAX  12943360u  // 4

// ---- seq f32 -> bf16 ----
__global__ void k_cvt_seq(const float* __restrict__ seq, short* __restrict__ seqb) {
  int i = (blockIdx.x * 256 + threadIdx.x) * 4;
  float4 v = *(const float4*)(seq + i);
  uint2 o; o.x = pk2(v.x, v.y); o.y = pk2(v.z, v.w);
  *(uint2*)(seqb + i) = o;
}

// ---- W[512,256] -> WT bf16 [256,512] ----
__global__ void k_wt(const float* __restrict__ W, short* __restrict__ WTb) {
  int h = blockIdx.x;
  int t = threadIdx.x;
  int k = t * 2;
  float w0 = W[k * 256 + h], w1 = W[(k + 1) * 256 + h];
  ((uint32_t*)(WTb + h * 512))[t] = pk2(w0, w1);
}

// ---- projection GEMM: fts = seq@W; epilogue writes PACKED SWIZZLED ftsP, f1, f2, f2max ----
// ftsP layout: per 64-node tile (32KB = 16384 shorts): [h 0..255][slot 0..7][8 bf16]
//   slot s of row h holds nodes j = tile*64 + (s^(h&7))*8 .. +7  (XOR bank swizzle)
__global__ __launch_bounds__(256) void k_proj(
    const short* __restrict__ seqb, const short* __restrict__ WTb,
    const float* __restrict__ a1, const float* __restrict__ b1,
    const float* __restrict__ a2, const float* __restrict__ b2,
    short* __restrict__ ftsP, float* __restrict__ f1g, float* __restrict__ f2g,
    uint32_t* __restrict__ f2maxenc) {
  __shared__ short At[64][72];
  __shared__ float f1a[64], f2a[64];
  const int t = threadIdx.x;
  const int l = t & 63, w = t >> 6;
  const int lr = l & 15, lg = l >> 4;
  const int R0 = blockIdx.x * 64;
  const int srow = t >> 2, scol = (t & 3) * 16;
  f32x4 acc[4][4] = {};
  if (t < 64) { f1a[t] = 0.f; f2a[t] = 0.f; }
  for (int kt = 0; kt < FIN; kt += 64) {
    uint4 s0 = *(const uint4*)(seqb + (size_t)(R0 + srow) * FIN + kt + scol);
    uint4 s1 = *(const uint4*)(seqb + (size_t)(R0 + srow) * FIN + kt + scol + 8);
    __syncthreads();
    *(uint4*)&At[srow][scol] = s0;
    *(uint4*)&At[srow][scol + 8] = s1;
    __syncthreads();
#pragma unroll
    for (int kk = 0; kk < 2; ++kk) {
      bf16x8 af[4];
#pragma unroll
      for (int mf = 0; mf < 4; ++mf)
        af[mf] = *(const bf16x8*)&At[mf * 16 + lr][kk * 32 + lg * 8];
#pragma unroll
      for (int nf = 0; nf < 4; ++nf) {
        int h = w * 64 + nf * 16 + lr;
        bf16x8 bfr = *(const bf16x8*)(WTb + h * FIN + kt + kk * 32 + lg * 8);
#pragma unroll
        for (int mf = 0; mf < 4; ++mf)
          acc[mf][nf] = __builtin_amdgcn_mfma_f32_16x16x32_bf16(af[mf], bfr, acc[mf][nf], 0, 0, 0);
      }
    }
  }
  __syncthreads();
  float a1v[4], a2v[4];
#pragma unroll
  for (int nf = 0; nf < 4; ++nf) {
    int h = w * 64 + nf * 16 + lr;
    a1v[nf] = a1[h]; a2v[nf] = a2[h];
  }
#pragma unroll
  for (int mf = 0; mf < 4; ++mf) {
    const int jo = mf * 16 + lg * 4;            // node offset within this 64-tile
    const int slot = (jo >> 3) ^ (lr & 7);      // h&7 == lr&7 (h = mult-of-8 + lr... w*64,nf*16 are mult of 8)
#pragma unroll
    for (int nf = 0; nf < 4; ++nf) {
      int h = w * 64 + nf * 16 + lr;
      uint2 o; o.x = pk2(acc[mf][nf][0], acc[mf][nf][1]);
      o.y = pk2(acc[mf][nf][2], acc[mf][nf][3]);
      *(uint2*)(ftsP + (size_t)blockIdx.x * 16384 + h * 64 + slot * 8 + (jo & 7)) = o;
    }
#pragma unroll
    for (int e = 0; e < 4; ++e) {
      float p1 = 0.f, p2 = 0.f;
#pragma unroll
      for (int nf = 0; nf < 4; ++nf) { p1 += acc[mf][nf][e] * a1v[nf]; p2 += acc[mf][nf][e] * a2v[nf]; }
#pragma unroll
      for (int m = 8; m >= 1; m >>= 1) { p1 += __shfl_xor(p1, m, 16); p2 += __shfl_xor(p2, m, 16); }
      if (lr == 0) {
        atomicAdd(&f1a[mf * 16 + lg * 4 + e], p1);
        atomicAdd(&f2a[mf * 16 + lg * 4 + e], p2);
      }
    }
  }
  __syncthreads();
  if (t < 64) {
    float v1 = f1a[t] + b1[0];
    float v2 = f2a[t] + b2[0];
    f1g[R0 + t] = v1; f2g[R0 + t] = v2;
    uint32_t u = __float_as_uint(v2);
    u = (u & 0x80000000u) ? ~u : (u | 0x80000000u);
    atomicMax(f2maxenc, u);
  }
}

// ---- fused flash: E in A-frag regs; V via double-buffered swizzled LDS; 1 barrier/tile ----
// 256 thr = 4 waves, 64 rows/block (wave owns 16 rows x 256 h). Grid (128 i, 4 j-chunks).
__global__ __launch_bounds__(256, 2) void k_flash(
    const float* __restrict__ bias, const short* __restrict__ ftsP,
    const float* __restrict__ f1g, const float* __restrict__ f2g,
    const uint32_t* __restrict__ f2maxenc,
    float* __restrict__ outacc, float* __restrict__ Zg) {
  __shared__ short Vb[2][16384];  // 2 x 32KB double buffer
  const int t = threadIdx.x;
  const int l = t & 63, wid = t >> 6;
  const int lr = l & 15, lg = l >> 4;
  const int rbase = blockIdx.x * 64 + wid * 16;
  const int rowA = rbase + lr;
  const int jbase = blockIdx.y * 2048;
  const int jt0 = jbase >> 6;      // global tile index base
  const int NT = 32;

  uint32_t ue = *f2maxenc;
  float f2mx = __uint_as_float((ue & 0x80000000u) ? (ue ^ 0x80000000u) : ~ue);
  float f1v = f1g[rowA];
  float xm = f1v + f2mx;
  float mr = fmaxf(xm, 0.2f * xm);  // exact row max (bias<=0, lrelu monotone)

  const float* bp = bias + (size_t)rowA * NN + jbase + lg * 8;
  const float* qp = f2g + jbase + lg * 8;
  const short* pp = ftsP + wid * 4096 + l * 8;  // + tile*16384 + c*512

  const int s0 = lg ^ (lr & 7);     // kk=0 slot
  const int s1 = s0 ^ 4;            // kk=1 slot
  const int ldsWoff = wid * 4096 + l * 8;

  f32x4 acc[16] = {};
  float z = 0.f;
  uint4 vr[8];
  float4 bb[2][2], qq[2][2];

#define LOADV(TT)                                                             \
  if ((TT) < NT) {                                                            \
    _Pragma("unroll")                                                         \
    for (int c = 0; c < 8; ++c)                                               \
      vr[c] = *(const uint4*)(pp + (size_t)(jt0 + (TT)) * 16384 + c * 512);   \
  }
#define LOADB(TT)                                                             \
  if ((TT) < NT) {                                                            \
    _Pragma("unroll")                                                         \
    for (int kk = 0; kk < 2; ++kk) {                                          \
      _Pragma("unroll")                                                       \
      for (int h = 0; h < 2; ++h) {                                           \
        bb[kk][h] = *(const float4*)(bp + (TT) * 64 + kk * 32 + h * 4);       \
        qq[kk][h] = *(const float4*)(qp + (TT) * 64 + kk * 32 + h * 4);       \
      }                                                                       \
    }                                                                         \
  }
#define WRITEV(BUF)                                                           \
  {                                                                           \
    _Pragma("unroll")                                                         \
    for (int c = 0; c < 8; ++c)                                               \
      *(uint4*)&Vb[(BUF)][ldsWoff + c * 512] = vr[c];                         \
  }

  // prologue: tile0 -> buf0; start tile1 loads; bias tile0 in regs
  LOADV(0)
  LOADB(0)
  WRITEV(0)
  LOADV(1)

  for (int tt = 0; tt < NT; ++tt) {
    // ---- E tile tt in A-frag layout (regs only) ----
    bf16x8 A0, A1;
    {
      float p[8];
#pragma unroll
      for (int e = 0; e < 4; ++e) {
        float s = f1v + ((const float*)&qq[0][0])[e];
        float ls = fmaxf(s, 0.2f * s);
        p[e] = __expf(ls + ((const float*)&bb[0][0])[e] - mr);
      }
#pragma unroll
      for (int e = 0; e < 4; ++e) {
        float s = f1v + ((const float*)&qq[0][1])[e];
        float ls = fmaxf(s, 0.2f * s);
        p[4 + e] = __expf(ls + ((const float*)&bb[0][1])[e] - mr);
      }
      z += ((p[0] + p[1]) + (p[2] + p[3])) + ((p[4] + p[5]) + (p[6] + p[7]));
      union { bf16x8 v; uint32_t u[4]; } A;
      A.u[0] = pk2(p[0], p[1]); A.u[1] = pk2(p[2], p[3]);
      A.u[2] = pk2(p[4], p[5]); A.u[3] = pk2(p[6], p[7]);
      A0 = A.v;
    }
    {
      float p[8];
#pragma unroll
      for (int e = 0; e < 4; ++e) {
        float s = f1v + ((const float*)&qq[1][0])[e];
        float ls = fmaxf(s, 0.2f * s);
        p[e] = __expf(ls + ((const float*)&bb[1][0])[e] - mr);
      }
#pragma unroll
      for (int e = 0; e < 4; ++e) {
        float s = f1v + ((const float*)&qq[1][1])[e];
        float ls = fmaxf(s, 0.2f * s);
        p[4 + e] = __expf(ls + ((const float*)&bb[1][1])[e] - mr);
      }
      z += ((p[0] + p[1]) + (p[2] + p[3])) + ((p[4] + p[5]) + (p[6] + p[7]));
      union { bf16x8 v; uint32_t u[4]; } A;
      A.u[0] = pk2(p[0], p[1]); A.u[1] = pk2(p[2], p[3]);
      A.u[2] = pk2(p[4], p[5]); A.u[3] = pk2(p[6], p[7]);
      A1 = A.v;
    }

    // ---- barrier: publishes buf[tt&1] (written last iter), drains V loads ----
    __syncthreads();

    // ---- stage tile tt+1 into buf[(tt+1)&1]; start loads for tt+2 and bias tt+1 ----
    if (tt + 1 < NT) {
      const int nb = (tt + 1) & 1;
      WRITEV(nb)
    }
    LOADV(tt + 2)
    LOADB(tt + 1)

    // ---- MFMA phase on buf[tt&1] (conflict-free swizzled ds_read_b128) ----
    {
      const int cb = tt & 1;
      const short* vr0 = &Vb[cb][lr * 64 + s0 * 8];
      const short* vr1 = &Vb[cb][lr * 64 + s1 * 8];
#pragma unroll
      for (int nf = 0; nf < 16; ++nf) {
        bf16x8 B0 = *(const bf16x8*)(vr0 + nf * 1024);
        acc[nf] = __builtin_amdgcn_mfma_f32_16x16x32_bf16(A0, B0, acc[nf], 0, 0, 0);
      }
#pragma unroll
      for (int nf = 0; nf < 16; ++nf) {
        bf16x8 B1 = *(const bf16x8*)(vr1 + nf * 1024);
        acc[nf] = __builtin_amdgcn_mfma_f32_16x16x32_bf16(A1, B1, acc[nf], 0, 0, 0);
      }
    }
  }
#undef LOADV
#undef LOADB
#undef WRITEV

  // Z partials (lanes sharing row lr: lg groups)
  z += __shfl_xor(z, 16);
  z += __shfl_xor(z, 32);
  if (lg == 0) atomicAdd(&Zg[rowA], z);

  // numerator partials (C layout: row = lg*4+e, col = nf*16+lr)
#pragma unroll
  for (int nf = 0; nf < 16; ++nf) {
    int col = nf * 16 + lr;
#pragma unroll
    for (int e = 0; e < 4; ++e)
      atomicAdd(&outacc[(size_t)(rbase + lg * 4 + e) * HID + col], acc[nf][e]);
  }
}

// ---- finalize: out = elu(num/Z + bias_zero) ----
__global__ void k_final(float* __restrict__ outp, const float* __restrict__ Zg,
                        const float* __restrict__ bz) {
  int i4 = (blockIdx.x * 256 + threadIdx.x) * 4;
  int row = i4 >> 8;
  int col = i4 & 255;
  float4 v = *(float4*)(outp + i4);
  float zr = 1.0f / Zg[row];
  float4 b = *(const float4*)(bz + col);
  float r[4] = {v.x * zr + b.x, v.y * zr + b.y, v.z * zr + b.z, v.w * zr + b.w};
#pragma unroll
  for (int e = 0; e < 4; ++e) r[e] = r[e] > 0.f ? r[e] : (__expf(r[e]) - 1.f);
  *(float4*)(outp + i4) = make_float4(r[0], r[1], r[2], r[3]);
}

extern "C" void kernel_launch(void* const* d_in, const int* in_sizes, int n_in,
                              void* d_out, int out_size, void* d_ws, size_t ws_size,
                              hipStream_t stream) {
  const float* seq  = (const float*)d_in[0];
  const float* bias = (const float*)d_in[1];
  const float* W    = (const float*)d_in[2];
  const float* a1   = (const float*)d_in[3];
  const float* b1   = (const float*)d_in[4];
  const float* a2   = (const float*)d_in[5];
  const float* b2   = (const float*)d_in[6];
  const float* bz   = (const float*)d_in[7];
  float* out = (float*)d_out;
  char* ws = (char*)d_ws;
  short* seqb = (short*)(ws + OFF_SEQB);
  short* WTb  = (short*)(ws + OFF_WTB);
  short* ftsP = (short*)(ws + OFF_FTST);
  float* f1g  = (float*)(ws + OFF_F1);
  float* f2g  = (float*)(ws + OFF_F2);
  float* Zg   = (float*)(ws + OFF_Z);
  uint32_t* f2m = (uint32_t*)(ws + OFF_F2MAX);

  hipMemsetAsync(d_out, 0, (size_t)NN * HID * 4, stream);
  hipMemsetAsync(Zg, 0, NN * 4, stream);
  hipMemsetAsync(f2m, 0, 4, stream);

  k_cvt_seq<<<4096, 256, 0, stream>>>(seq, seqb);
  k_wt<<<256, 256, 0, stream>>>(W, WTb);
  k_proj<<<128, 256, 0, stream>>>(seqb, WTb, a1, b1, a2, b2, ftsP, f1g, f2g, f2m);
  k_flash<<<dim3(128, 4), 256, 0, stream>>>(bias, ftsP, f1g, f2g, f2m, out, Zg);
  k_final<<<2048, 256, 0, stream>>>(out, Zg, bz);
}

// Round 5
// 156.809 us; speedup vs baseline: 2.6798x; 1.6747x over previous
//
#include <hip/hip_runtime.h>
#include <hip/hip_bf16.h>
#include <stdint.h>

#define NN 8192
#define FIN 512
#define HID 256

typedef short bf16x8 __attribute__((ext_vector_type(8)));
typedef float f32x4 __attribute__((ext_vector_type(4)));

__device__ __forceinline__ uint32_t pk2(float lo, float hi) {
  uint32_t a = __float_as_uint(lo), b = __float_as_uint(hi);
  a = (a + 0x7FFFu + ((a >> 16) & 1u)) >> 16;
  b = (b + 0x7FFFu + ((b >> 16) & 1u)) >> 16;
  return a | (b << 16);
}

// workspace byte offsets
#define OFF_SEQB   0u         // 8192*512*2  = 8388608
#define OFF_WTB    8388608u   // 256*512*2   = 262144
#define OFF_FTST   8650752u   // 256*8192*2  = 4194304 (packed swizzled tiles)
#define OFF_F1     12845056u  // 8192*4
#define OFF_F2     12877824u  // 8192*4
#define OFF_Z      12910592u  // 8192*4
#define OFF_F2MAX  12943360u  // 4

// ---- seq f32 -> bf16 ----
__global__ void k_cvt_seq(const float* __restrict__ seq, short* __restrict__ seqb) {
  int i = (blockIdx.x * 256 + threadIdx.x) * 4;
  float4 v = *(const float4*)(seq + i);
  uint2 o; o.x = pk2(v.x, v.y); o.y = pk2(v.z, v.w);
  *(uint2*)(seqb + i) = o;
}

// ---- W[512,256] -> WT bf16 [256,512] ----
__global__ void k_wt(const float* __restrict__ W, short* __restrict__ WTb) {
  int h = blockIdx.x;
  int t = threadIdx.x;
  int k = t * 2;
  float w0 = W[k * 256 + h], w1 = W[(k + 1) * 256 + h];
  ((uint32_t*)(WTb + h * 512))[t] = pk2(w0, w1);
}

// ---- projection GEMM: fts = seq@W; epilogue writes PACKED SWIZZLED ftsP, f1, f2, f2max ----
// ftsP layout: per 64-node tile (32KB = 16384 shorts): [h 0..255][slot 0..7][8 bf16]
//   slot s of row h holds nodes j = tile*64 + (s^(h&7))*8 .. +7  (XOR bank swizzle)
__global__ __launch_bounds__(256) void k_proj(
    const short* __restrict__ seqb, const short* __restrict__ WTb,
    const float* __restrict__ a1, const float* __restrict__ b1,
    const float* __restrict__ a2, const float* __restrict__ b2,
    short* __restrict__ ftsP, float* __restrict__ f1g, float* __restrict__ f2g,
    uint32_t* __restrict__ f2maxenc) {
  __shared__ short At[64][72];
  __shared__ float f1a[64], f2a[64];
  const int t = threadIdx.x;
  const int l = t & 63, w = t >> 6;
  const int lr = l & 15, lg = l >> 4;
  const int R0 = blockIdx.x * 64;
  const int srow = t >> 2, scol = (t & 3) * 16;
  f32x4 acc[4][4] = {};
  if (t < 64) { f1a[t] = 0.f; f2a[t] = 0.f; }
  for (int kt = 0; kt < FIN; kt += 64) {
    uint4 s0 = *(const uint4*)(seqb + (size_t)(R0 + srow) * FIN + kt + scol);
    uint4 s1 = *(const uint4*)(seqb + (size_t)(R0 + srow) * FIN + kt + scol + 8);
    __syncthreads();
    *(uint4*)&At[srow][scol] = s0;
    *(uint4*)&At[srow][scol + 8] = s1;
    __syncthreads();
#pragma unroll
    for (int kk = 0; kk < 2; ++kk) {
      bf16x8 af[4];
#pragma unroll
      for (int mf = 0; mf < 4; ++mf)
        af[mf] = *(const bf16x8*)&At[mf * 16 + lr][kk * 32 + lg * 8];
#pragma unroll
      for (int nf = 0; nf < 4; ++nf) {
        int h = w * 64 + nf * 16 + lr;
        bf16x8 bfr = *(const bf16x8*)(WTb + h * FIN + kt + kk * 32 + lg * 8);
#pragma unroll
        for (int mf = 0; mf < 4; ++mf)
          acc[mf][nf] = __builtin_amdgcn_mfma_f32_16x16x32_bf16(af[mf], bfr, acc[mf][nf], 0, 0, 0);
      }
    }
  }
  __syncthreads();
  float a1v[4], a2v[4];
#pragma unroll
  for (int nf = 0; nf < 4; ++nf) {
    int h = w * 64 + nf * 16 + lr;
    a1v[nf] = a1[h]; a2v[nf] = a2[h];
  }
#pragma unroll
  for (int mf = 0; mf < 4; ++mf) {
    const int jo = mf * 16 + lg * 4;
    const int slot = (jo >> 3) ^ (lr & 7);
#pragma unroll
    for (int nf = 0; nf < 4; ++nf) {
      int h = w * 64 + nf * 16 + lr;
      uint2 o; o.x = pk2(acc[mf][nf][0], acc[mf][nf][1]);
      o.y = pk2(acc[mf][nf][2], acc[mf][nf][3]);
      *(uint2*)(ftsP + (size_t)blockIdx.x * 16384 + h * 64 + slot * 8 + (jo & 7)) = o;
    }
#pragma unroll
    for (int e = 0; e < 4; ++e) {
      float p1 = 0.f, p2 = 0.f;
#pragma unroll
      for (int nf = 0; nf < 4; ++nf) { p1 += acc[mf][nf][e] * a1v[nf]; p2 += acc[mf][nf][e] * a2v[nf]; }
#pragma unroll
      for (int m = 8; m >= 1; m >>= 1) { p1 += __shfl_xor(p1, m, 16); p2 += __shfl_xor(p2, m, 16); }
      if (lr == 0) {
        atomicAdd(&f1a[mf * 16 + lg * 4 + e], p1);
        atomicAdd(&f2a[mf * 16 + lg * 4 + e], p2);
      }
    }
  }
  __syncthreads();
  if (t < 64) {
    float v1 = f1a[t] + b1[0];
    float v2 = f2a[t] + b2[0];
    f1g[R0 + t] = v1; f2g[R0 + t] = v2;
    uint32_t u = __float_as_uint(v2);
    u = (u & 0x80000000u) ? ~u : (u | 0x80000000u);
    atomicMax(f2maxenc, u);
  }
}

// ---- fused flash: E in A-frag regs; V tiles via global_load_lds double-buffer; 1 barrier/tile ----
// 256 thr = 4 waves, 64 rows/block (wave owns 16 rows x 256 h). Grid (128 i, 4 j-chunks) = 2 blocks/CU.
__global__ __launch_bounds__(256, 2) void k_flash(
    const float* __restrict__ bias, const short* __restrict__ ftsP,
    const float* __restrict__ f1g, const float* __restrict__ f2g,
    const uint32_t* __restrict__ f2maxenc,
    float* __restrict__ outacc, float* __restrict__ Zg) {
  __shared__ short Vb[2][16384];  // 2 x 32KB double buffer
  const int t = threadIdx.x;
  const int l = t & 63, wid = t >> 6;
  const int lr = l & 15, lg = l >> 4;
  const int rbase = blockIdx.x * 64 + wid * 16;
  const int rowA = rbase + lr;
  const int jbase = blockIdx.y * 2048;
  const int jt0 = jbase >> 6;
  const int NT = 32;

  uint32_t ue = *f2maxenc;
  float f2mx = __uint_as_float((ue & 0x80000000u) ? (ue ^ 0x80000000u) : ~ue);
  float f1v = f1g[rowA];
  float xm = f1v + f2mx;
  float mr = fmaxf(xm, 0.2f * xm);  // exact row max (bias<=0, lrelu monotone)

  const float* bp = bias + (size_t)rowA * NN + jbase + lg * 8;
  const float* qp = f2g + jbase + lg * 8;

  const int s0 = lg ^ (lr & 7);   // kk=0 slot (conflict-free, verified: 0 bank conflicts in R4)
  const int s1 = s0 ^ 4;          // kk=1 slot

  f32x4 acc[16] = {};
  float z = 0.f;
  float4 bb[2][2], qq[2][2];      // current tile bias/f2 (static-indexed only)
  float4 nb[2][2], nq[2][2];      // next tile

  // stage: wave wid copies its 8KB quarter of the 32KB tile straight to LDS (no VGPRs)
#define STAGE(TT, BUF)                                                          \
  if ((TT) < NT) {                                                              \
    const short* gs = ftsP + (size_t)(jt0 + (TT)) * 16384 + wid * 4096 + l * 8; \
    _Pragma("unroll")                                                           \
    for (int c = 0; c < 8; ++c)                                                 \
      __builtin_amdgcn_global_load_lds(                                         \
          (const __attribute__((address_space(1))) void*)(gs + c * 512),        \
          (__attribute__((address_space(3))) void*)&Vb[(BUF)][wid * 4096 + c * 512], \
          16, 0, 0);                                                            \
  }
#define LOADB(TT, B, Q)                                                         \
  if ((TT) < NT) {                                                              \
    _Pragma("unroll")                                                           \
    for (int kk = 0; kk < 2; ++kk) {                                            \
      _Pragma("unroll")                                                         \
      for (int h = 0; h < 2; ++h) {                                             \
        B[kk][h] = *(const float4*)(bp + (TT) * 64 + kk * 32 + h * 4);          \
        Q[kk][h] = *(const float4*)(qp + (TT) * 64 + kk * 32 + h * 4);          \
      }                                                                         \
    }                                                                           \
  }

  // prologue: tiles 0,1 -> LDS; bias tile 0 -> regs; drain all
  STAGE(0, 0)
  STAGE(1, 1)
  LOADB(0, bb, qq)
  __syncthreads();

  for (int tt = 0; tt < NT; ++tt) {
    // issue next-tile bias/f2 loads early (slack = E + MFMA phases)
    LOADB(tt + 1, nb, nq)

    // ---- E tile tt in A-frag layout (regs only) ----
    bf16x8 A0, A1;
    {
      float p[8];
#pragma unroll
      for (int e = 0; e < 4; ++e) {
        float s = f1v + ((const float*)&qq[0][0])[e];
        float ls = fmaxf(s, 0.2f * s);
        p[e] = __expf(ls + ((const float*)&bb[0][0])[e] - mr);
      }
#pragma unroll
      for (int e = 0; e < 4; ++e) {
        float s = f1v + ((const float*)&qq[0][1])[e];
        float ls = fmaxf(s, 0.2f * s);
        p[4 + e] = __expf(ls + ((const float*)&bb[0][1])[e] - mr);
      }
      z += ((p[0] + p[1]) + (p[2] + p[3])) + ((p[4] + p[5]) + (p[6] + p[7]));
      union { bf16x8 v; uint32_t u[4]; } A;
      A.u[0] = pk2(p[0], p[1]); A.u[1] = pk2(p[2], p[3]);
      A.u[2] = pk2(p[4], p[5]); A.u[3] = pk2(p[6], p[7]);
      A0 = A.v;
    }
    {
      float p[8];
#pragma unroll
      for (int e = 0; e < 4; ++e) {
        float s = f1v + ((const float*)&qq[1][0])[e];
        float ls = fmaxf(s, 0.2f * s);
        p[e] = __expf(ls + ((const float*)&bb[1][0])[e] - mr);
      }
#pragma unroll
      for (int e = 0; e < 4; ++e) {
        float s = f1v + ((const float*)&qq[1][1])[e];
        float ls = fmaxf(s, 0.2f * s);
        p[4 + e] = __expf(ls + ((const float*)&bb[1][1])[e] - mr);
      }
      z += ((p[0] + p[1]) + (p[2] + p[3])) + ((p[4] + p[5]) + (p[6] + p[7]));
      union { bf16x8 v; uint32_t u[4]; } A;
      A.u[0] = pk2(p[0], p[1]); A.u[1] = pk2(p[2], p[3]);
      A.u[2] = pk2(p[4], p[5]); A.u[3] = pk2(p[6], p[7]);
      A1 = A.v;
    }

    // ---- MFMA phase on buf[tt&1] (conflict-free swizzled ds_read_b128) ----
    {
      const int cb = tt & 1;
      const short* vr0 = &Vb[cb][lr * 64 + s0 * 8];
      const short* vr1 = &Vb[cb][lr * 64 + s1 * 8];
#pragma unroll
      for (int nf = 0; nf < 16; ++nf) {
        bf16x8 B0 = *(const bf16x8*)(vr0 + nf * 1024);
        acc[nf] = __builtin_amdgcn_mfma_f32_16x16x32_bf16(A0, B0, acc[nf], 0, 0, 0);
      }
#pragma unroll
      for (int nf = 0; nf < 16; ++nf) {
        bf16x8 B1 = *(const bf16x8*)(vr1 + nf * 1024);
        acc[nf] = __builtin_amdgcn_mfma_f32_16x16x32_bf16(A1, B1, acc[nf], 0, 0, 0);
      }
    }

    // ---- all waves done reading buf[tt&1]; restage it with tile tt+2 ----
    __syncthreads();
    STAGE(tt + 2, tt & 1)

    // rotate bias regs (fully static)
#pragma unroll
    for (int kk = 0; kk < 2; ++kk)
#pragma unroll
      for (int h = 0; h < 2; ++h) { bb[kk][h] = nb[kk][h]; qq[kk][h] = nq[kk][h]; }
  }
#undef STAGE
#undef LOADB

  // Z partials (lanes sharing row lr: lg groups)
  z += __shfl_xor(z, 16);
  z += __shfl_xor(z, 32);
  if (lg == 0) atomicAdd(&Zg[rowA], z);

  // numerator partials (C layout: row = lg*4+e, col = nf*16+lr)
#pragma unroll
  for (int nf = 0; nf < 16; ++nf) {
    int col = nf * 16 + lr;
#pragma unroll
    for (int e = 0; e < 4; ++e)
      atomicAdd(&outacc[(size_t)(rbase + lg * 4 + e) * HID + col], acc[nf][e]);
  }
}

// ---- finalize: out = elu(num/Z + bias_zero) ----
__global__ void k_final(float* __restrict__ outp, const float* __restrict__ Zg,
                        const float* __restrict__ bz) {
  int i4 = (blockIdx.x * 256 + threadIdx.x) * 4;
  int row = i4 >> 8;
  int col = i4 & 255;
  float4 v = *(float4*)(outp + i4);
  float zr = 1.0f / Zg[row];
  float4 b = *(const float4*)(bz + col);
  float r[4] = {v.x * zr + b.x, v.y * zr + b.y, v.z * zr + b.z, v.w * zr + b.w};
#pragma unroll
  for (int e = 0; e < 4; ++e) r[e] = r[e] > 0.f ? r[e] : (__expf(r[e]) - 1.f);
  *(float4*)(outp + i4) = make_float4(r[0], r[1], r[2], r[3]);
}

extern "C" void kernel_launch(void* const* d_in, const int* in_sizes, int n_in,
                              void* d_out, int out_size, void* d_ws, size_t ws_size,
                              hipStream_t stream) {
  const float* seq  = (const float*)d_in[0];
  const float* bias = (const float*)d_in[1];
  const float* W    = (const float*)d_in[2];
  const float* a1   = (const float*)d_in[3];
  const float* b1   = (const float*)d_in[4];
  const float* a2   = (const float*)d_in[5];
  const float* b2   = (const float*)d_in[6];
  const float* bz   = (const float*)d_in[7];
  float* out = (float*)d_out;
  char* ws = (char*)d_ws;
  short* seqb = (short*)(ws + OFF_SEQB);
  short* WTb  = (short*)(ws + OFF_WTB);
  short* ftsP = (short*)(ws + OFF_FTST);
  float* f1g  = (float*)(ws + OFF_F1);
  float* f2g  = (float*)(ws + OFF_F2);
  float* Zg   = (float*)(ws + OFF_Z);
  uint32_t* f2m = (uint32_t*)(ws + OFF_F2MAX);

  hipMemsetAsync(d_out, 0, (size_t)NN * HID * 4, stream);
  hipMemsetAsync(Zg, 0, NN * 4, stream);
  hipMemsetAsync(f2m, 0, 4, stream);

  k_cvt_seq<<<4096, 256, 0, stream>>>(seq, seqb);
  k_wt<<<256, 256, 0, stream>>>(W, WTb);
  k_proj<<<128, 256, 0, stream>>>(seqb, WTb, a1, b1, a2, b2, ftsP, f1g, f2g, f2m);
  k_flash<<<dim3(128, 4), 256, 0, stream>>>(bias, ftsP, f1g, f2g, f2m, out, Zg);
  k_final<<<2048, 256, 0, stream>>>(out, Zg, bz);
}